// Round 7
// baseline (79.312 us; speedup 1.0000x reference)
//
#include <hip/hip_runtime.h>
#include <hip/hip_bf16.h>

// 3x3 s1 p1 conv: B=16, CIN=128, H=W=56, COUT=256, K = 9*128.
// Pipeline: (1) wreorder3: W fp32 -> bf16, K-tile/frag-linear wb3 (+zero page)
//           (2) nhwc:      X fp32 NCHW -> bf16 NHWC xin[b][y][x][c]
//           (3) conv7:     8-phase 256x256 implicit GEMM (T3+T4+T5):
//               196 blocks x 512 thr (8 waves, 2Mx4N), BK=64 (tap x 64ch),
//               4 phases/K-tile, raw s_barrier + counted-late vmcnt, 128KB LDS.
#define CIN_   128
#define HW_    56
#define LHW_   3136
#define COUT_  256
#define KTOT_  1152

typedef unsigned short u16;
typedef __attribute__((ext_vector_type(8))) short short8v;   // 8 bf16
typedef __attribute__((ext_vector_type(4))) float f32x4;

__device__ __forceinline__ u16 f2bf(float f) {
  union { float f; unsigned u; } v; v.f = f;
  unsigned u = v.u;
  u += 0x7fffu + ((u >> 16) & 1u);   // RNE
  return (u16)(u >> 16);
}
__device__ __forceinline__ unsigned pack2(u16 a, u16 b) {
  return (unsigned)a | ((unsigned)b << 16);
}

// ---- (1) K-tile-major weight reorder + zero page.
// 16B chunk s = (kt*8 + kgrp)*256 + o  holds w[o][c*9+t] for
// t = kt>>1, c = (kt&1)*64 + kgrp*8 + 0..7  (8 bf16, k ascending).
__global__ void wreorder3_kernel(const float* __restrict__ w, u16* __restrict__ wb3,
                                 u16* __restrict__ zp) {
  if (blockIdx.x == 0 && threadIdx.x < 16) {
    uint4 z; z.x = z.y = z.z = z.w = 0u;
    reinterpret_cast<uint4*>(zp)[threadIdx.x] = z;   // 256B zero page
  }
  int j = blockIdx.x * 256 + threadIdx.x;   // 73728 = 2 * 36864
  int half = j & 1;
  int s    = j >> 1;            // chunk 0..36863
  int o    = s & 255;
  int kg8  = s >> 8;            // 0..143
  int kt   = kg8 >> 3;
  int kgrp = kg8 & 7;
  int t    = kt >> 1;
  int c    = ((kt & 1) << 6) + kgrp * 8 + half * 4;
  const float* src = w + (size_t)o * KTOT_ + (size_t)c * 9 + t;
  ushort4 r;
  r.x = f2bf(src[0]);  r.y = f2bf(src[9]);
  r.z = f2bf(src[18]); r.w = f2bf(src[27]);
  *reinterpret_cast<ushort4*>(wb3 + (size_t)s * 8 + half * 4) = r;
}

// ---- legacy weight reorder for fallback A: wb[(t*256+o)*128 + c]
__global__ void wreorder_kernel(const float* __restrict__ w, u16* __restrict__ wb) {
  int j = blockIdx.x * 256 + threadIdx.x;
  int c4 = j & 31;
  int o  = (j >> 5) & 255;
  int t  = j >> 13;
  const float* src = w + (size_t)o * KTOT_ + t;
  ushort4 r;
  r.x = f2bf(src[(c4 * 4 + 0) * 9]);
  r.y = f2bf(src[(c4 * 4 + 1) * 9]);
  r.z = f2bf(src[(c4 * 4 + 2) * 9]);
  r.w = f2bf(src[(c4 * 4 + 3) * 9]);
  *reinterpret_cast<ushort4*>(wb + ((size_t)(t * 256 + o) * 128 + c4 * 4)) = r;
}

// ---- (2) NCHW fp32 -> NHWC bf16 transpose (LDS-tiled, 64 pos x 128 ch)
#define TLDSW_ 136
__global__ __launch_bounds__(256) void nhwc_kernel(
    const float* __restrict__ in, u16* __restrict__ xin) {
  __shared__ u16 ts[64 * TLDSW_];
  const int bp = blockIdx.x;          // 784 = 16 * 49
  const int b = bp / 49;
  const int pos0 = (bp % 49) * 64;
  const int tid = threadIdx.x;
  const float* ib = in + (size_t)b * CIN_ * LHW_ + pos0;
  {
    const int p  = tid & 63;
    const int c0 = (tid >> 6) * 32;
    #pragma unroll
    for (int i = 0; i < 32; ++i)
      ts[p * TLDSW_ + c0 + i] = f2bf(ib[(size_t)(c0 + i) * LHW_ + p]);
  }
  __syncthreads();
  {
    const int p  = tid >> 2;
    const int c0 = (tid & 3) * 32;
    u16* dst = xin + ((size_t)b * LHW_ + pos0 + p) * CIN_ + c0;
    const u16* srcr = &ts[p * TLDSW_ + c0];
    #pragma unroll
    for (int j = 0; j < 4; ++j)
      reinterpret_cast<uint4*>(dst)[j] =
          *reinterpret_cast<const uint4*>(srcr + j * 8);
  }
}

// ---- (3) main conv: 8-phase schedule
__device__ __forceinline__ void gload_lds16(const void* g, void* l) {
  __builtin_amdgcn_global_load_lds(
      (const __attribute__((address_space(1))) void*)g,
      (__attribute__((address_space(3))) void*)l, 16, 0, 0);
}

__global__ __launch_bounds__(512, 2) void conv7_kernel(
    const u16* __restrict__ xin, const u16* __restrict__ wb3,
    const float* __restrict__ bias, const u16* __restrict__ zpage,
    float* __restrict__ out)
{
  // per K-tile: A = 256co x 64k, B = 256sp x 64k, frag-linear chunks:
  // chunk(kgrp, i) at LDS byte (kgrp*256 + i)*16, kgrp = k-group of 8.
  __shared__ __align__(16) u16 alds[2][16384];   // 2 x 32 KB
  __shared__ __align__(16) u16 blds[2][16384];   // 2 x 32 KB  -> 128 KB total

  const int tid  = threadIdx.x;
  const int lane = tid & 63;
  const int wid  = tid >> 6;
  const int wm   = wid & 1;     // co half (128)
  const int wn   = wid >> 1;    // sp quarter (64)
  const int lr   = lane & 15;
  const int lg   = lane >> 4;

  const int nt = blockIdx.x;    // 0..195 spatial tile of 256 positions

  // ---- B staging geometry: this thread stages position sp, kgroups kg0+{0,2,4,6}
  const int sp  = tid & 255;
  const int kg0 = tid >> 8;     // 0/1
  const int n   = nt * 256 + sp;
  const int ll  = n % LHW_;
  const int py  = ll / HW_;
  const int px  = ll - py * HW_;
  const u16* xpos = xin + (size_t)n * CIN_ + (kg0 << 3);
  unsigned okm = 0;
  #pragma unroll
  for (int t = 0; t < 9; ++t) {
    int yy = py + t / 3 - 1, xx = px + t % 3 - 1;
    if ((unsigned)yy < (unsigned)HW_ && (unsigned)xx < (unsigned)HW_)
      okm |= 1u << t;
  }

  const int ldsoff = (tid & ~63) * 8;   // u16 offset of this thread's chunk base

  auto stage = [&](int kt, int h) {
    // A: linear stream from wb3 (4 chunks: tid + q*512)
    const u16* sa = wb3 + ((size_t)kt * 2048 + tid) * 8;
    u16* da = alds[h] + ldsoff;
    #pragma unroll
    for (int q = 0; q < 4; ++q)
      gload_lds16(sa + q * 4096, da + q * 4096);
    // B: NHWC gather at tap offset (4 chunks: same position, kgrp += 2)
    const int t    = kt >> 1;
    const int dy   = t / 3, dx = t - dy * 3;
    const int doff = ((dy - 1) * HW_ + (dx - 1)) * CIN_ + ((kt & 1) << 6);
    const bool ok  = (okm >> t) & 1;
    const u16* sb  = ok ? xpos + doff : zpage;
    u16* db = blds[h] + ldsoff;
    #pragma unroll
    for (int q = 0; q < 4; ++q)
      gload_lds16(sb + q * 16, db + q * 4096);
  };

  // frag LDS bases (u16 units). slot(kgrp, idx) = kgrp*256 + idx, addr = slot*8.
  const int abase = (lg * 256 + wm * 128 + lr) * 8;
  const int bbase = (lg * 256 + wn * 64 + lr) * 8;

  f32x4 acc[8][4];
  #pragma unroll
  for (int i = 0; i < 8; ++i)
    #pragma unroll
    for (int j = 0; j < 4; ++j)
      acc[i][j] = f32x4{0.f, 0.f, 0.f, 0.f};

  short8v Af[8];            // current A-half: [kk*4 + ai]
  short8v Bf0[4], Bf1[4];   // B halves:      [kk*2 + nj]

#define READ_A(h, half)                                                         \
  { _Pragma("unroll") for (int kk = 0; kk < 2; ++kk)                            \
    _Pragma("unroll") for (int ai = 0; ai < 4; ++ai)                            \
      Af[kk * 4 + ai] = *reinterpret_cast<const short8v*>(                      \
          &alds[h][abase + kk * 8192 + ((half) * 4 + ai) * 128]); }
#define READ_B(h, half, Bf)                                                     \
  { _Pragma("unroll") for (int kk = 0; kk < 2; ++kk)                            \
    _Pragma("unroll") for (int nj = 0; nj < 2; ++nj)                            \
      (Bf)[kk * 2 + nj] = *reinterpret_cast<const short8v*>(                    \
          &blds[h][bbase + kk * 8192 + ((half) * 2 + nj) * 128]); }
#define PHASE_SYNC()                                                            \
  __builtin_amdgcn_sched_barrier(0);                                            \
  __builtin_amdgcn_s_barrier();                                                 \
  asm volatile("s_waitcnt lgkmcnt(0)" ::: "memory");                            \
  __builtin_amdgcn_sched_barrier(0);
#define MFMA16(ah, bh, Bf)                                                      \
  { __builtin_amdgcn_s_setprio(1);                                              \
    _Pragma("unroll") for (int kk = 0; kk < 2; ++kk)                            \
    _Pragma("unroll") for (int ai = 0; ai < 4; ++ai)                            \
    _Pragma("unroll") for (int nj = 0; nj < 2; ++nj)                            \
      acc[(ah) * 4 + ai][(bh) * 2 + nj] = __builtin_amdgcn_mfma_f32_16x16x32_bf16( \
          Af[kk * 4 + ai], (Bf)[kk * 2 + nj], acc[(ah) * 4 + ai][(bh) * 2 + nj], \
          0, 0, 0);                                                             \
    __builtin_amdgcn_s_setprio(0);                                              \
    __builtin_amdgcn_sched_barrier(0);                                          \
    __builtin_amdgcn_s_barrier(); }

  // prologue: stage K-tile 0, drain, sync
  stage(0, 0);
  asm volatile("s_waitcnt vmcnt(0)" ::: "memory");
  __builtin_amdgcn_s_barrier();

  #pragma unroll 1
  for (int kt = 0; kt < 18; ++kt) {
    const int h = kt & 1;
    // P0: prefetch next K-tile (stays in flight 3 phases) + A0,B0 reads
    if (kt < 17) stage(kt + 1, h ^ 1);
    READ_A(h, 0); READ_B(h, 0, Bf0);
    PHASE_SYNC();
    MFMA16(0, 0, Bf0);
    // P1: B1 reads
    READ_B(h, 1, Bf1);
    PHASE_SYNC();
    MFMA16(0, 1, Bf1);
    // P2: A1 reads (overwrite Af)
    READ_A(h, 1);
    PHASE_SYNC();
    MFMA16(1, 0, Bf0);
    // P3: no reads; boundary drain (loads are ~3 phases old)
    MFMA16(1, 1, Bf1);
    asm volatile("s_waitcnt vmcnt(0)" ::: "memory");
    __builtin_amdgcn_s_barrier();
  }

  // epilogue: D col = lr (spatial), row = lg*4+rr (cout)
  #pragma unroll
  for (int nj = 0; nj < 4; ++nj) {
    const int nb0 = nt * 256 + wn * 64 + nj * 16;   // 16-aligned, LHW_%16==0
    const int ob  = nb0 / LHW_;
    const int ol  = nb0 - ob * LHW_;
    float* obp = out + (size_t)ob * COUT_ * LHW_ + ol + lr;
    #pragma unroll
    for (int ai = 0; ai < 8; ++ai) {
      const int o = wm * 128 + ai * 16 + lg * 4;
      const float4 bs = *reinterpret_cast<const float4*>(&bias[o]);
      obp[(size_t)(o + 0) * LHW_] = acc[ai][nj][0] + bs.x;
      obp[(size_t)(o + 1) * LHW_] = acc[ai][nj][1] + bs.y;
      obp[(size_t)(o + 2) * LHW_] = acc[ai][nj][2] + bs.z;
      obp[(size_t)(o + 3) * LHW_] = acc[ai][nj][3] + bs.w;
    }
  }
#undef READ_A
#undef READ_B
#undef PHASE_SYNC
#undef MFMA16
}

// ---------------- fallback A (ws fits wb only): round-2 kernel ----
#define NF_    7
#define SCOLS_ 58
#define SPP_   232
#define CSTR_  128
__global__ __launch_bounds__(256, 2) void conv2_kernel(
    const float* __restrict__ in, const u16* __restrict__ wb,
    const float* __restrict__ bias, float* __restrict__ out)
{
  __shared__ u16 xs[SPP_ * CSTR_];
  const int tid  = threadIdx.x;
  const int lane = tid & 63;
  const int wid  = tid >> 6;
  const int lr   = lane & 15;
  const int lg   = lane >> 4;
  const int bid = blockIdx.x;
  const int ch  = bid & 1;
  const int ty  = (bid >> 1) % 28;
  const int b   = bid / 56;
  const float* inb = in + (size_t)b * CIN_ * LHW_;
  const int iy0 = ty * 2 - 1;

  #pragma unroll 1
  for (int i = 0; i < 15; ++i) {
    int idx = i * 256 + tid;
    if (idx < SPP_ * 16) {
      int cg  = idx / SPP_;
      int spp = idx - cg * SPP_;
      int rr  = spp / SCOLS_;
      int cc  = spp - rr * SCOLS_;
      int iy  = iy0 + rr;
      int ix  = cc - 1;
      bool ok = ((unsigned)iy < (unsigned)HW_) && ((unsigned)ix < (unsigned)HW_);
      const float* pp = inb + (size_t)cg * 8 * LHW_ + iy * HW_ + ix;
      u16 v[8];
      #pragma unroll
      for (int jj = 0; jj < 8; ++jj)
        v[jj] = f2bf(ok ? pp[jj * LHW_] : 0.f);
      uint4 pk;
      pk.x = pack2(v[0], v[1]); pk.y = pack2(v[2], v[3]);
      pk.z = pack2(v[4], v[5]); pk.w = pack2(v[6], v[7]);
      *reinterpret_cast<uint4*>(&xs[spp * CSTR_ + ((cg * 8) ^ ((spp & 7) << 3))]) = pk;
    }
  }
  int spp0[NF_];
  #pragma unroll
  for (int nf = 0; nf < NF_; ++nf) {
    int sp = nf * 16 + lr;
    int r  = (sp >= 56) ? 1 : 0;
    int x  = sp - r * 56;
    spp0[nf] = (r + 1) * SCOLS_ + x + 1;
  }
  f32x4 acc[2][NF_];
  #pragma unroll
  for (int m = 0; m < 2; ++m)
    #pragma unroll
    for (int nf = 0; nf < NF_; ++nf)
      acc[m][nf] = f32x4{0.f, 0.f, 0.f, 0.f};
  __syncthreads();
  const u16* wt0 = wb + (size_t)(ch * 128 + wid * 32 + lr) * CSTR_ + lg * 8;
  #pragma unroll 1
  for (int t = 0; t < 9; ++t) {
    const int dspp = (t / 3 - 1) * SCOLS_ + (t % 3 - 1);
    const u16* wt = wt0 + (size_t)t * 256 * CSTR_;
    #pragma unroll
    for (int c0i = 0; c0i < 4; ++c0i) {
      const int c0 = c0i * 32;
      short8v a0 = *reinterpret_cast<const short8v*>(wt + c0);
      short8v a1 = *reinterpret_cast<const short8v*>(wt + 16 * CSTR_ + c0);
      short8v bv[NF_];
      #pragma unroll
      for (int nf = 0; nf < NF_; ++nf) {
        int spp = spp0[nf] + dspp;
        int off = spp * CSTR_ + ((c0 + lg * 8) ^ ((spp & 7) << 3));
        bv[nf] = *reinterpret_cast<const short8v*>(&xs[off]);
      }
      #pragma unroll
      for (int nf = 0; nf < NF_; ++nf) {
        acc[0][nf] = __builtin_amdgcn_mfma_f32_16x16x32_bf16(a0, bv[nf], acc[0][nf], 0, 0, 0);
        acc[1][nf] = __builtin_amdgcn_mfma_f32_16x16x32_bf16(a1, bv[nf], acc[1][nf], 0, 0, 0);
      }
    }
  }
  float* ob = out + (size_t)b * COUT_ * LHW_ + ty * 112;
  const int obase = ch * 128 + wid * 32 + lg * 4;
  #pragma unroll
  for (int m = 0; m < 2; ++m)
    #pragma unroll
    for (int rr = 0; rr < 4; ++rr) {
      const int o = obase + m * 16 + rr;
      const float bs = bias[o];
      #pragma unroll
      for (int nf = 0; nf < NF_; ++nf)
        ob[(size_t)o * LHW_ + nf * 16 + lr] = acc[m][nf][rr] + bs;
    }
}

// ---------------- fallback B (no ws at all): fp32-weight direct ----
#define SPT0_  64
#define BK0_   32
#define NKS0_  36
#define LDSW0_ 40
__global__ __launch_bounds__(256, 2) void conv_fb_kernel(
    const float* __restrict__ in, const float* __restrict__ wf,
    const float* __restrict__ bias, float* __restrict__ out)
{
  __shared__ u16 xs[SPT0_ * LDSW0_];
  const int tid = threadIdx.x;
  const int lane = tid & 63;
  const int wid = tid >> 6;
  const int lg = lane >> 4;
  const int lr = lane & 15;
  const int bid = blockIdx.x;
  const int b = bid / 49;
  const int l0 = (bid % 49) * SPT0_;
  const int sp = tid & 63;
  const int qq = tid >> 6;
  const int l = l0 + sp;
  const int y = l / HW_;
  const int x = l - y * HW_;
  const float* inb = in + (size_t)b * CIN_ * LHW_;
  f32x4 acc[4][4];
  #pragma unroll
  for (int i = 0; i < 4; ++i)
    #pragma unroll
    for (int j = 0; j < 4; ++j) acc[i][j] = f32x4{0.f, 0.f, 0.f, 0.f};
  auto stage_load = [&](int ks) -> uint4 {
    int kbase = ks * BK0_ + qq * 8;
    int c = kbase / 9;
    int t = kbase - c * 9;
    u16 v[8];
    #pragma unroll
    for (int j = 0; j < 8; ++j) {
      int dy = (t * 11) >> 5;
      int dx = t - 3 * dy;
      int yy = y + dy - 1, xx = x + dx - 1;
      float f = 0.f;
      if ((unsigned)yy < (unsigned)HW_ && (unsigned)xx < (unsigned)HW_)
        f = inb[(c * HW_ + yy) * HW_ + xx];
      v[j] = f2bf(f);
      ++t; if (t == 9) { t = 0; ++c; }
    }
    uint4 r;
    r.x = pack2(v[0], v[1]); r.y = pack2(v[2], v[3]);
    r.z = pack2(v[4], v[5]); r.w = pack2(v[6], v[7]);
    return r;
  };
  uint4 st = stage_load(0);
  for (int ks = 0; ks < NKS0_; ++ks) {
    __syncthreads();
    *reinterpret_cast<uint4*>(&xs[sp * LDSW0_ + qq * 8]) = st;
    __syncthreads();
    if (ks + 1 < NKS0_) st = stage_load(ks + 1);
    const int k0 = ks * BK0_;
    short8v a[4];
    #pragma unroll
    for (int ai = 0; ai < 4; ++ai) {
      const int o = wid * 64 + ai * 16 + lr;
      const float* pp = wf + (size_t)o * KTOT_ + k0 + lg * 8;
      u16 t8[8];
      #pragma unroll
      for (int j = 0; j < 8; ++j) t8[j] = f2bf(pp[j]);
      union { uint4 u; short8v s; } cv;
      cv.u.x = pack2(t8[0], t8[1]); cv.u.y = pack2(t8[2], t8[3]);
      cv.u.z = pack2(t8[4], t8[5]); cv.u.w = pack2(t8[6], t8[7]);
      a[ai] = cv.s;
    }
    short8v bv[4];
    #pragma unroll
    for (int sj = 0; sj < 4; ++sj)
      bv[sj] = *reinterpret_cast<const short8v*>(&xs[(sj * 16 + lr) * LDSW0_ + lg * 8]);
    #pragma unroll
    for (int ai = 0; ai < 4; ++ai)
      #pragma unroll
      for (int sj = 0; sj < 4; ++sj)
        acc[ai][sj] = __builtin_amdgcn_mfma_f32_16x16x32_bf16(a[ai], bv[sj], acc[ai][sj], 0, 0, 0);
  }
  float* outb = out + (size_t)b * COUT_ * LHW_ + l0;
  #pragma unroll
  for (int ai = 0; ai < 4; ++ai)
    #pragma unroll
    for (int r = 0; r < 4; ++r) {
      const int o = wid * 64 + ai * 16 + lg * 4 + r;
      const float bvs = bias[o];
      #pragma unroll
      for (int sj = 0; sj < 4; ++sj)
        outb[(size_t)o * LHW_ + sj * 16 + lr] = acc[ai][sj][r] + bvs;
    }
}

extern "C" void kernel_launch(void* const* d_in, const int* in_sizes, int n_in,
                              void* d_out, int out_size, void* d_ws, size_t ws_size,
                              hipStream_t stream) {
  (void)in_sizes; (void)n_in; (void)out_size;
  const float* in   = (const float*)d_in[0];
  const float* w    = (const float*)d_in[1];
  const float* bias = (const float*)d_in[2];
  float* out = (float*)d_out;

  const size_t wbytes  = (size_t)COUT_ * KTOT_ * sizeof(u16);        // 589824
  const size_t xbytes  = (size_t)16 * LHW_ * CIN_ * sizeof(u16);     // 12845056
  const size_t need    = wbytes + xbytes + 256;

  if (ws_size >= need) {
    u16* wb3 = (u16*)d_ws;
    u16* xin = wb3 + wbytes / 2;
    u16* zp  = xin + xbytes / 2;
    wreorder3_kernel<<<dim3(288), dim3(256), 0, stream>>>(w, wb3, zp);
    nhwc_kernel<<<dim3(784), dim3(256), 0, stream>>>(in, xin);
    conv7_kernel<<<dim3(196), dim3(512), 0, stream>>>(xin, wb3, bias, zp, out);
  } else if (ws_size >= wbytes) {
    u16* wb = (u16*)d_ws;
    wreorder_kernel<<<dim3(288), dim3(256), 0, stream>>>(w, wb);
    conv2_kernel<<<dim3(896), dim3(256), 0, stream>>>(in, wb, bias, out);
  } else {
    conv_fb_kernel<<<dim3(784), dim3(256), 0, stream>>>(in, w, bias, out);
  }
}

// Round 8
// 78.750 us; speedup vs baseline: 1.0071x; 1.0071x over previous
//
#include <hip/hip_runtime.h>
#include <hip/hip_bf16.h>

// 3x3 s1 p1 conv: B=16, CIN=128, H=W=56, COUT=256, K = 9*128.
// Pipeline: (1) wreorder3: W fp32 -> bf16, K-tile/frag-linear wb3 (+zero page)
//           (2) nhwc:      X fp32 NCHW -> bf16 NHWC xin[b][y][x][c]
//           (3) conv8:     8-phase 256x256 implicit GEMM (T3+T4+T5):
//               196 blocks x 512 thr (8 waves, 2Mx4N), BK=64 (tap x 64ch),
//               4 phases/K-tile, raw s_barrier + COUNTED vmcnt(8) (loads stay
//               in flight across the whole K-tile), 128KB LDS.
#define CIN_   128
#define HW_    56
#define LHW_   3136
#define COUT_  256
#define KTOT_  1152

typedef unsigned short u16;
typedef __attribute__((ext_vector_type(8))) short short8v;   // 8 bf16
typedef __attribute__((ext_vector_type(4))) float f32x4;

__device__ __forceinline__ u16 f2bf(float f) {
  union { float f; unsigned u; } v; v.f = f;
  unsigned u = v.u;
  u += 0x7fffu + ((u >> 16) & 1u);   // RNE
  return (u16)(u >> 16);
}
__device__ __forceinline__ unsigned pack2(u16 a, u16 b) {
  return (unsigned)a | ((unsigned)b << 16);
}

// ---- (1) K-tile-major weight reorder + zero page.
// 16B chunk s = (kt*8 + kgrp)*256 + o  holds w[o][c*9+t] for
// t = kt>>1, c = (kt&1)*64 + kgrp*8 + 0..7  (8 bf16, k ascending).
__global__ void wreorder3_kernel(const float* __restrict__ w, u16* __restrict__ wb3,
                                 u16* __restrict__ zp) {
  if (blockIdx.x == 0 && threadIdx.x < 16) {
    uint4 z; z.x = z.y = z.z = z.w = 0u;
    reinterpret_cast<uint4*>(zp)[threadIdx.x] = z;   // 256B zero page
  }
  int j = blockIdx.x * 256 + threadIdx.x;   // 73728 = 2 * 36864
  int half = j & 1;
  int s    = j >> 1;            // chunk 0..36863
  int o    = s & 255;
  int kg8  = s >> 8;            // 0..143
  int kt   = kg8 >> 3;
  int kgrp = kg8 & 7;
  int t    = kt >> 1;
  int c    = ((kt & 1) << 6) + kgrp * 8 + half * 4;
  const float* src = w + (size_t)o * KTOT_ + (size_t)c * 9 + t;
  ushort4 r;
  r.x = f2bf(src[0]);  r.y = f2bf(src[9]);
  r.z = f2bf(src[18]); r.w = f2bf(src[27]);
  *reinterpret_cast<ushort4*>(wb3 + (size_t)s * 8 + half * 4) = r;
}

// ---- legacy weight reorder for fallback A: wb[(t*256+o)*128 + c]
__global__ void wreorder_kernel(const float* __restrict__ w, u16* __restrict__ wb) {
  int j = blockIdx.x * 256 + threadIdx.x;
  int c4 = j & 31;
  int o  = (j >> 5) & 255;
  int t  = j >> 13;
  const float* src = w + (size_t)o * KTOT_ + t;
  ushort4 r;
  r.x = f2bf(src[(c4 * 4 + 0) * 9]);
  r.y = f2bf(src[(c4 * 4 + 1) * 9]);
  r.z = f2bf(src[(c4 * 4 + 2) * 9]);
  r.w = f2bf(src[(c4 * 4 + 3) * 9]);
  *reinterpret_cast<ushort4*>(wb + ((size_t)(t * 256 + o) * 128 + c4 * 4)) = r;
}

// ---- (2) NCHW fp32 -> NHWC bf16 transpose (LDS-tiled, 64 pos x 128 ch)
#define TLDSW_ 136
__global__ __launch_bounds__(256) void nhwc_kernel(
    const float* __restrict__ in, u16* __restrict__ xin) {
  __shared__ u16 ts[64 * TLDSW_];
  const int bp = blockIdx.x;          // 784 = 16 * 49
  const int b = bp / 49;
  const int pos0 = (bp % 49) * 64;
  const int tid = threadIdx.x;
  const float* ib = in + (size_t)b * CIN_ * LHW_ + pos0;
  {
    const int p  = tid & 63;
    const int c0 = (tid >> 6) * 32;
    #pragma unroll
    for (int i = 0; i < 32; ++i)
      ts[p * TLDSW_ + c0 + i] = f2bf(ib[(size_t)(c0 + i) * LHW_ + p]);
  }
  __syncthreads();
  {
    const int p  = tid >> 2;
    const int c0 = (tid & 3) * 32;
    u16* dst = xin + ((size_t)b * LHW_ + pos0 + p) * CIN_ + c0;
    const u16* srcr = &ts[p * TLDSW_ + c0];
    #pragma unroll
    for (int j = 0; j < 4; ++j)
      reinterpret_cast<uint4*>(dst)[j] =
          *reinterpret_cast<const uint4*>(srcr + j * 8);
  }
}

// ---- (3) main conv: 8-phase schedule with counted vmcnt
__device__ __forceinline__ void gload_lds16(const void* g, void* l) {
  __builtin_amdgcn_global_load_lds(
      (const __attribute__((address_space(1))) void*)g,
      (__attribute__((address_space(3))) void*)l, 16, 0, 0);
}

__global__ __launch_bounds__(512, 2) void conv8_kernel(
    const u16* __restrict__ xin, const u16* __restrict__ wb3,
    const float* __restrict__ bias, const u16* __restrict__ zpage,
    float* __restrict__ out)
{
  // per K-tile: A = 256co x 64k, B = 256sp x 64k, frag-linear chunks:
  // chunk(kgrp, i) at LDS byte (kgrp*256 + i)*16, kgrp = k-group of 8.
  __shared__ __align__(16) u16 alds[2][16384];   // 2 x 32 KB
  __shared__ __align__(16) u16 blds[2][16384];   // 2 x 32 KB  -> 128 KB total

  const int tid  = threadIdx.x;
  const int lane = tid & 63;
  const int wid  = tid >> 6;
  const int wm   = wid & 1;     // co half (128)
  const int wn   = wid >> 1;    // sp quarter (64)
  const int lr   = lane & 15;
  const int lg   = lane >> 4;

  const int nt = blockIdx.x;    // 0..195 spatial tile of 256 positions

  // ---- B staging geometry: this thread stages position sp, kgroups kg0+{0,2,4,6}
  const int sp  = tid & 255;
  const int kg0 = tid >> 8;     // 0/1
  const int n   = nt * 256 + sp;
  const int ll  = n % LHW_;
  const int py  = ll / HW_;
  const int px  = ll - py * HW_;
  const u16* xpos = xin + (size_t)n * CIN_ + (kg0 << 3);
  unsigned okm = 0;
  #pragma unroll
  for (int t = 0; t < 9; ++t) {
    int yy = py + t / 3 - 1, xx = px + t % 3 - 1;
    if ((unsigned)yy < (unsigned)HW_ && (unsigned)xx < (unsigned)HW_)
      okm |= 1u << t;
  }

  const int ldsoff = (tid & ~63) * 8;   // u16 offset of this thread's chunk base

  auto stage = [&](int kt, int h) {
    // A: linear stream from wb3 (4 chunks: tid + q*512)
    const u16* sa = wb3 + ((size_t)kt * 2048 + tid) * 8;
    u16* da = alds[h] + ldsoff;
    #pragma unroll
    for (int q = 0; q < 4; ++q)
      gload_lds16(sa + q * 4096, da + q * 4096);
    // B: NHWC gather at tap offset (4 chunks: same position, kgrp += 2)
    const int t    = kt >> 1;
    const int dy   = t / 3, dx = t - dy * 3;
    const int doff = ((dy - 1) * HW_ + (dx - 1)) * CIN_ + ((kt & 1) << 6);
    const bool ok  = (okm >> t) & 1;
    const u16* sb  = ok ? xpos + doff : zpage;
    u16* db = blds[h] + ldsoff;
    #pragma unroll
    for (int q = 0; q < 4; ++q)
      gload_lds16(sb + q * 16, db + q * 4096);
  };

  // frag LDS bases (u16 units). slot(kgrp, idx) = kgrp*256 + idx, addr = slot*8.
  const int abase = (lg * 256 + wm * 128 + lr) * 8;
  const int bbase = (lg * 256 + wn * 64 + lr) * 8;

  f32x4 acc[8][4];
  #pragma unroll
  for (int i = 0; i < 8; ++i)
    #pragma unroll
    for (int j = 0; j < 4; ++j)
      acc[i][j] = f32x4{0.f, 0.f, 0.f, 0.f};

  short8v Af[8];            // current A-half: [kk*4 + ai]
  short8v Bf0[4], Bf1[4];   // B halves:      [kk*2 + nj]

#define READ_A(h, half)                                                         \
  { _Pragma("unroll") for (int kk = 0; kk < 2; ++kk)                            \
    _Pragma("unroll") for (int ai = 0; ai < 4; ++ai)                            \
      Af[kk * 4 + ai] = *reinterpret_cast<const short8v*>(                      \
          &alds[h][abase + kk * 8192 + ((half) * 4 + ai) * 128]); }
#define READ_B(h, half, Bf)                                                     \
  { _Pragma("unroll") for (int kk = 0; kk < 2; ++kk)                            \
    _Pragma("unroll") for (int nj = 0; nj < 2; ++nj)                            \
      (Bf)[kk * 2 + nj] = *reinterpret_cast<const short8v*>(                    \
          &blds[h][bbase + kk * 8192 + ((half) * 2 + nj) * 128]); }
#define PHASE_SYNC()                                                            \
  __builtin_amdgcn_sched_barrier(0);                                            \
  __builtin_amdgcn_s_barrier();                                                 \
  asm volatile("s_waitcnt lgkmcnt(0)" ::: "memory");                            \
  __builtin_amdgcn_sched_barrier(0);
#define MFMA16(ah, bh, Bf)                                                      \
  { __builtin_amdgcn_s_setprio(1);                                              \
    _Pragma("unroll") for (int kk = 0; kk < 2; ++kk)                            \
    _Pragma("unroll") for (int ai = 0; ai < 4; ++ai)                            \
    _Pragma("unroll") for (int nj = 0; nj < 2; ++nj)                            \
      acc[(ah) * 4 + ai][(bh) * 2 + nj] = __builtin_amdgcn_mfma_f32_16x16x32_bf16( \
          Af[kk * 4 + ai], (Bf)[kk * 2 + nj], acc[(ah) * 4 + ai][(bh) * 2 + nj], \
          0, 0, 0);                                                             \
    __builtin_amdgcn_s_setprio(0);                                              \
    __builtin_amdgcn_sched_barrier(0);                                          \
    __builtin_amdgcn_s_barrier(); }

  // prologue: issue K-tile 0 stage (no drain yet — counted wait in loop)
  stage(0, 0);

  #pragma unroll 1
  for (int kt = 0; kt < 18; ++kt) {
    const int h = kt & 1;
    // T4: issue next K-tile's 8 loads, then wait ONLY for the 8 oldest
    // (= this K-tile's loads). kt+1's loads stay in flight across all
    // 8 barriers of this K-tile.
    if (kt < 17) {
      stage(kt + 1, h ^ 1);
      asm volatile("s_waitcnt vmcnt(8)" ::: "memory");
    } else {
      asm volatile("s_waitcnt vmcnt(0)" ::: "memory");
    }
    __builtin_amdgcn_sched_barrier(0);
    __builtin_amdgcn_s_barrier();        // all waves: buffer h fully landed

    // P0
    READ_A(h, 0); READ_B(h, 0, Bf0);
    PHASE_SYNC();
    MFMA16(0, 0, Bf0);
    // P1
    READ_B(h, 1, Bf1);
    PHASE_SYNC();
    MFMA16(0, 1, Bf1);
    // P2
    READ_A(h, 1);
    PHASE_SYNC();
    MFMA16(1, 0, Bf0);
    // P3 (no reads)
    MFMA16(1, 1, Bf1);
  }

  // epilogue: D col = lr (spatial), row = lg*4+rr (cout)
  #pragma unroll
  for (int nj = 0; nj < 4; ++nj) {
    const int nb0 = nt * 256 + wn * 64 + nj * 16;   // 16-aligned, LHW_%16==0
    const int ob  = nb0 / LHW_;
    const int ol  = nb0 - ob * LHW_;
    float* obp = out + (size_t)ob * COUT_ * LHW_ + ol + lr;
    #pragma unroll
    for (int ai = 0; ai < 8; ++ai) {
      const int o = wm * 128 + ai * 16 + lg * 4;
      const float4 bs = *reinterpret_cast<const float4*>(&bias[o]);
      obp[(size_t)(o + 0) * LHW_] = acc[ai][nj][0] + bs.x;
      obp[(size_t)(o + 1) * LHW_] = acc[ai][nj][1] + bs.y;
      obp[(size_t)(o + 2) * LHW_] = acc[ai][nj][2] + bs.z;
      obp[(size_t)(o + 3) * LHW_] = acc[ai][nj][3] + bs.w;
    }
  }
#undef READ_A
#undef READ_B
#undef PHASE_SYNC
#undef MFMA16
}

// ---------------- fallback A (ws fits wb only): round-2 kernel ----
#define NF_    7
#define SCOLS_ 58
#define SPP_   232
#define CSTR_  128
__global__ __launch_bounds__(256, 2) void conv2_kernel(
    const float* __restrict__ in, const u16* __restrict__ wb,
    const float* __restrict__ bias, float* __restrict__ out)
{
  __shared__ u16 xs[SPP_ * CSTR_];
  const int tid  = threadIdx.x;
  const int lane = tid & 63;
  const int wid  = tid >> 6;
  const int lr   = lane & 15;
  const int lg   = lane >> 4;
  const int bid = blockIdx.x;
  const int ch  = bid & 1;
  const int ty  = (bid >> 1) % 28;
  const int b   = bid / 56;
  const float* inb = in + (size_t)b * CIN_ * LHW_;
  const int iy0 = ty * 2 - 1;

  #pragma unroll 1
  for (int i = 0; i < 15; ++i) {
    int idx = i * 256 + tid;
    if (idx < SPP_ * 16) {
      int cg  = idx / SPP_;
      int spp = idx - cg * SPP_;
      int rr  = spp / SCOLS_;
      int cc  = spp - rr * SCOLS_;
      int iy  = iy0 + rr;
      int ix  = cc - 1;
      bool ok = ((unsigned)iy < (unsigned)HW_) && ((unsigned)ix < (unsigned)HW_);
      const float* pp = inb + (size_t)cg * 8 * LHW_ + iy * HW_ + ix;
      u16 v[8];
      #pragma unroll
      for (int jj = 0; jj < 8; ++jj)
        v[jj] = f2bf(ok ? pp[jj * LHW_] : 0.f);
      uint4 pk;
      pk.x = pack2(v[0], v[1]); pk.y = pack2(v[2], v[3]);
      pk.z = pack2(v[4], v[5]); pk.w = pack2(v[6], v[7]);
      *reinterpret_cast<uint4*>(&xs[spp * CSTR_ + ((cg * 8) ^ ((spp & 7) << 3))]) = pk;
    }
  }
  int spp0[NF_];
  #pragma unroll
  for (int nf = 0; nf < NF_; ++nf) {
    int sp = nf * 16 + lr;
    int r  = (sp >= 56) ? 1 : 0;
    int x  = sp - r * 56;
    spp0[nf] = (r + 1) * SCOLS_ + x + 1;
  }
  f32x4 acc[2][NF_];
  #pragma unroll
  for (int m = 0; m < 2; ++m)
    #pragma unroll
    for (int nf = 0; nf < NF_; ++nf)
      acc[m][nf] = f32x4{0.f, 0.f, 0.f, 0.f};
  __syncthreads();
  const u16* wt0 = wb + (size_t)(ch * 128 + wid * 32 + lr) * CSTR_ + lg * 8;
  #pragma unroll 1
  for (int t = 0; t < 9; ++t) {
    const int dspp = (t / 3 - 1) * SCOLS_ + (t % 3 - 1);
    const u16* wt = wt0 + (size_t)t * 256 * CSTR_;
    #pragma unroll
    for (int c0i = 0; c0i < 4; ++c0i) {
      const int c0 = c0i * 32;
      short8v a0 = *reinterpret_cast<const short8v*>(wt + c0);
      short8v a1 = *reinterpret_cast<const short8v*>(wt + 16 * CSTR_ + c0);
      short8v bv[NF_];
      #pragma unroll
      for (int nf = 0; nf < NF_; ++nf) {
        int spp = spp0[nf] + dspp;
        int off = spp * CSTR_ + ((c0 + lg * 8) ^ ((spp & 7) << 3));
        bv[nf] = *reinterpret_cast<const short8v*>(&xs[off]);
      }
      #pragma unroll
      for (int nf = 0; nf < NF_; ++nf) {
        acc[0][nf] = __builtin_amdgcn_mfma_f32_16x16x32_bf16(a0, bv[nf], acc[0][nf], 0, 0, 0);
        acc[1][nf] = __builtin_amdgcn_mfma_f32_16x16x32_bf16(a1, bv[nf], acc[1][nf], 0, 0, 0);
      }
    }
  }
  float* ob = out + (size_t)b * COUT_ * LHW_ + ty * 112;
  const int obase = ch * 128 + wid * 32 + lg * 4;
  #pragma unroll
  for (int m = 0; m < 2; ++m)
    #pragma unroll
    for (int rr = 0; rr < 4; ++rr) {
      const int o = obase + m * 16 + rr;
      const float bs = bias[o];
      #pragma unroll
      for (int nf = 0; nf < NF_; ++nf)
        ob[(size_t)o * LHW_ + nf * 16 + lr] = acc[m][nf][rr] + bs;
    }
}

// ---------------- fallback B (no ws at all): fp32-weight direct ----
#define SPT0_  64
#define BK0_   32
#define NKS0_  36
#define LDSW0_ 40
__global__ __launch_bounds__(256, 2) void conv_fb_kernel(
    const float* __restrict__ in, const float* __restrict__ wf,
    const float* __restrict__ bias, float* __restrict__ out)
{
  __shared__ u16 xs[SPT0_ * LDSW0_];
  const int tid = threadIdx.x;
  const int lane = tid & 63;
  const int wid = tid >> 6;
  const int lg = lane >> 4;
  const int lr = lane & 15;
  const int bid = blockIdx.x;
  const int b = bid / 49;
  const int l0 = (bid % 49) * SPT0_;
  const int sp = tid & 63;
  const int qq = tid >> 6;
  const int l = l0 + sp;
  const int y = l / HW_;
  const int x = l - y * HW_;
  const float* inb = in + (size_t)b * CIN_ * LHW_;
  f32x4 acc[4][4];
  #pragma unroll
  for (int i = 0; i < 4; ++i)
    #pragma unroll
    for (int j = 0; j < 4; ++j) acc[i][j] = f32x4{0.f, 0.f, 0.f, 0.f};
  auto stage_load = [&](int ks) -> uint4 {
    int kbase = ks * BK0_ + qq * 8;
    int c = kbase / 9;
    int t = kbase - c * 9;
    u16 v[8];
    #pragma unroll
    for (int j = 0; j < 8; ++j) {
      int dy = (t * 11) >> 5;
      int dx = t - 3 * dy;
      int yy = y + dy - 1, xx = x + dx - 1;
      float f = 0.f;
      if ((unsigned)yy < (unsigned)HW_ && (unsigned)xx < (unsigned)HW_)
        f = inb[(c * HW_ + yy) * HW_ + xx];
      v[j] = f2bf(f);
      ++t; if (t == 9) { t = 0; ++c; }
    }
    uint4 r;
    r.x = pack2(v[0], v[1]); r.y = pack2(v[2], v[3]);
    r.z = pack2(v[4], v[5]); r.w = pack2(v[6], v[7]);
    return r;
  };
  uint4 st = stage_load(0);
  for (int ks = 0; ks < NKS0_; ++ks) {
    __syncthreads();
    *reinterpret_cast<uint4*>(&xs[sp * LDSW0_ + qq * 8]) = st;
    __syncthreads();
    if (ks + 1 < NKS0_) st = stage_load(ks + 1);
    const int k0 = ks * BK0_;
    short8v a[4];
    #pragma unroll
    for (int ai = 0; ai < 4; ++ai) {
      const int o = wid * 64 + ai * 16 + lr;
      const float* pp = wf + (size_t)o * KTOT_ + k0 + lg * 8;
      u16 t8[8];
      #pragma unroll
      for (int j = 0; j < 8; ++j) t8[j] = f2bf(pp[j]);
      union { uint4 u; short8v s; } cv;
      cv.u.x = pack2(t8[0], t8[1]); cv.u.y = pack2(t8[2], t8[3]);
      cv.u.z = pack2(t8[4], t8[5]); cv.u.w = pack2(t8[6], t8[7]);
      a[ai] = cv.s;
    }
    short8v bv[4];
    #pragma unroll
    for (int sj = 0; sj < 4; ++sj)
      bv[sj] = *reinterpret_cast<const short8v*>(&xs[(sj * 16 + lr) * LDSW0_ + lg * 8]);
    #pragma unroll
    for (int ai = 0; ai < 4; ++ai)
      #pragma unroll
      for (int sj = 0; sj < 4; ++sj)
        acc[ai][sj] = __builtin_amdgcn_mfma_f32_16x16x32_bf16(a[ai], bv[sj], acc[ai][sj], 0, 0, 0);
  }
  float* outb = out + (size_t)b * COUT_ * LHW_ + l0;
  #pragma unroll
  for (int ai = 0; ai < 4; ++ai)
    #pragma unroll
    for (int r = 0; r < 4; ++r) {
      const int o = wid * 64 + ai * 16 + lg * 4 + r;
      const float bvs = bias[o];
      #pragma unroll
      for (int sj = 0; sj < 4; ++sj)
        outb[(size_t)o * LHW_ + sj * 16 + lr] = acc[ai][sj][r] + bvs;
    }
}

extern "C" void kernel_launch(void* const* d_in, const int* in_sizes, int n_in,
                              void* d_out, int out_size, void* d_ws, size_t ws_size,
                              hipStream_t stream) {
  (void)in_sizes; (void)n_in; (void)out_size;
  const float* in   = (const float*)d_in[0];
  const float* w    = (const float*)d_in[1];
  const float* bias = (const float*)d_in[2];
  float* out = (float*)d_out;

  const size_t wbytes  = (size_t)COUT_ * KTOT_ * sizeof(u16);        // 589824
  const size_t xbytes  = (size_t)16 * LHW_ * CIN_ * sizeof(u16);     // 12845056
  const size_t need    = wbytes + xbytes + 256;

  if (ws_size >= need) {
    u16* wb3 = (u16*)d_ws;
    u16* xin = wb3 + wbytes / 2;
    u16* zp  = xin + xbytes / 2;
    wreorder3_kernel<<<dim3(288), dim3(256), 0, stream>>>(w, wb3, zp);
    nhwc_kernel<<<dim3(784), dim3(256), 0, stream>>>(in, xin);
    conv8_kernel<<<dim3(196), dim3(512), 0, stream>>>(xin, wb3, bias, zp, out);
  } else if (ws_size >= wbytes) {
    u16* wb = (u16*)d_ws;
    wreorder_kernel<<<dim3(288), dim3(256), 0, stream>>>(w, wb);
    conv2_kernel<<<dim3(896), dim3(256), 0, stream>>>(in, wb, bias, out);
  } else {
    conv_fb_kernel<<<dim3(784), dim3(256), 0, stream>>>(in, w, bias, out);
  }
}

// Round 9
// 71.102 us; speedup vs baseline: 1.1155x; 1.1076x over previous
//
#include <hip/hip_runtime.h>
#include <hip/hip_bf16.h>

// 3x3 s1 p1 conv: B=16, CIN=128, H=W=56, COUT=256, K = 9*128.
// Pipeline: (1) wreorder4: W fp32 -> bf16, phase-region-major wb4 (+zero page)
//           (2) nhwc:      X fp32 NCHW -> bf16 NHWC xin[b][y][x][c]
//           (3) conv9:     8-phase-faithful 256x256 implicit GEMM:
//               196 blocks x 512 thr (8 waves 2Mx4N), BK=64 (tap x 64ch),
//               4 phases/K-tile, 1 half-tile staged per phase (2 gload/thr),
//               counted vmcnt(2) once per K-tile, 7 barriers/K-tile, 128KB LDS.
#define CIN_   128
#define HW_    56
#define LHW_   3136
#define COUT_  256
#define KTOT_  1152

typedef unsigned short u16;
typedef __attribute__((ext_vector_type(8))) short short8v;   // 8 bf16
typedef __attribute__((ext_vector_type(4))) float f32x4;

__device__ __forceinline__ u16 f2bf(float f) {
  union { float f; unsigned u; } v; v.f = f;
  unsigned u = v.u;
  u += 0x7fffu + ((u >> 16) & 1u);   // RNE
  return (u16)(u >> 16);
}
__device__ __forceinline__ unsigned pack2(u16 a, u16 b) {
  return (unsigned)a | ((unsigned)b << 16);
}

// ---- (1) phase-region weight reorder + zero page.
// 16B chunk s = kt*2048 + kgrp*256 + phys, phys = half*128 + wm*64 + q:
// holds w[o][ch*9+t] for o = wm*128 + half*64 + q, ch = (kt&1)*64 + kgrp*8 + 0..7,
// t = kt>>1.  A-read-half H occupies phys in [H*128, H*128+128) -> stageable
// as one contiguous half-tile per phase.
__global__ void wreorder4_kernel(const float* __restrict__ w, u16* __restrict__ wb4,
                                 u16* __restrict__ zp) {
  if (blockIdx.x == 0 && threadIdx.x < 16) {
    uint4 z; z.x = z.y = z.z = z.w = 0u;
    reinterpret_cast<uint4*>(zp)[threadIdx.x] = z;   // 256B zero page
  }
  int v = blockIdx.x * 256 + threadIdx.x;   // 73728 = 2 * 36864
  int quad = v & 1;
  int s    = v >> 1;            // chunk 0..36863
  int phys = s & 255;
  int kgrp = (s >> 8) & 7;
  int kt   = s >> 11;
  int o    = ((phys >> 6) & 1) * 128 + (phys >> 7) * 64 + (phys & 63);
  int t    = kt >> 1;
  int ch   = ((kt & 1) << 6) + kgrp * 8 + quad * 4;
  const float* src = w + (size_t)o * KTOT_ + (size_t)ch * 9 + t;
  ushort4 r;
  r.x = f2bf(src[0]);  r.y = f2bf(src[9]);
  r.z = f2bf(src[18]); r.w = f2bf(src[27]);
  *reinterpret_cast<ushort4*>(wb4 + (size_t)s * 8 + quad * 4) = r;
}

// ---- legacy weight reorder for fallback A: wb[(t*256+o)*128 + c]
__global__ void wreorder_kernel(const float* __restrict__ w, u16* __restrict__ wb) {
  int j = blockIdx.x * 256 + threadIdx.x;
  int c4 = j & 31;
  int o  = (j >> 5) & 255;
  int t  = j >> 13;
  const float* src = w + (size_t)o * KTOT_ + t;
  ushort4 r;
  r.x = f2bf(src[(c4 * 4 + 0) * 9]);
  r.y = f2bf(src[(c4 * 4 + 1) * 9]);
  r.z = f2bf(src[(c4 * 4 + 2) * 9]);
  r.w = f2bf(src[(c4 * 4 + 3) * 9]);
  *reinterpret_cast<ushort4*>(wb + ((size_t)(t * 256 + o) * 128 + c4 * 4)) = r;
}

// ---- (2) NCHW fp32 -> NHWC bf16 transpose (LDS-tiled, 64 pos x 128 ch)
#define TLDSW_ 136
__global__ __launch_bounds__(256) void nhwc_kernel(
    const float* __restrict__ in, u16* __restrict__ xin) {
  __shared__ u16 ts[64 * TLDSW_];
  const int bp = blockIdx.x;          // 784 = 16 * 49
  const int b = bp / 49;
  const int pos0 = (bp % 49) * 64;
  const int tid = threadIdx.x;
  const float* ib = in + (size_t)b * CIN_ * LHW_ + pos0;
  {
    const int p  = tid & 63;
    const int c0 = (tid >> 6) * 32;
    #pragma unroll
    for (int i = 0; i < 32; ++i)
      ts[p * TLDSW_ + c0 + i] = f2bf(ib[(size_t)(c0 + i) * LHW_ + p]);
  }
  __syncthreads();
  {
    const int p  = tid >> 2;
    const int c0 = (tid & 3) * 32;
    u16* dst = xin + ((size_t)b * LHW_ + pos0 + p) * CIN_ + c0;
    const u16* srcr = &ts[p * TLDSW_ + c0];
    #pragma unroll
    for (int j = 0; j < 4; ++j)
      reinterpret_cast<uint4*>(dst)[j] =
          *reinterpret_cast<const uint4*>(srcr + j * 8);
  }
}

// ---- (3) main conv
__device__ __forceinline__ void gload_lds16(const void* g, void* l) {
  __builtin_amdgcn_global_load_lds(
      (const __attribute__((address_space(1))) void*)g,
      (__attribute__((address_space(3))) void*)l, 16, 0, 0);
}

__global__ __launch_bounds__(512, 2) void conv9_kernel(
    const u16* __restrict__ xin, const u16* __restrict__ wb4,
    const float* __restrict__ bias, const u16* __restrict__ zpage,
    float* __restrict__ out)
{
  // A tile 256co x 64k, B tile 256sp x 64k; chunk (kgrp, phys) at u16 offset
  // (kgrp*256 + phys)*8.  A phys = half*128 + wm*64 + (ai*16+lr);
  // B phys = half*128 + wn*32 + (nj*16+lr)  [sp = wn*64 + half*32 + nj*16 + lr].
  __shared__ __align__(16) u16 alds[2][16384];   // 2 x 32 KB
  __shared__ __align__(16) u16 blds[2][16384];   // 2 x 32 KB  -> 128 KB

  const int tid  = threadIdx.x;
  const int lane = tid & 63;
  const int wid  = tid >> 6;
  const int wm   = wid & 1;     // co half (128)
  const int wn   = wid >> 1;    // sp quarter (64)
  const int lr   = lane & 15;
  const int lg   = lane >> 4;

  const int nt = blockIdx.x;    // 0..195 spatial tile of 256 positions

  // ---- staging geometry ----
  const int jC = tid >> 7;      // kgrp base (0..3); second chunk kgrp = jC+4
  const int t7 = tid & 127;

  // B: this thread stages positions sp0 (half0) and sp0+32 (half1)
  const int sp0 = ((t7 >> 5) & 3) * 64 + (t7 & 31);
  unsigned okm0 = 0, okm1 = 0;
  const u16 *xp0, *xp1;
  {
    int n0 = nt * 256 + sp0;
    int l0 = n0 % LHW_;
    int y0 = l0 / HW_, x0 = l0 - y0 * HW_;
    int n1 = n0 + 32;
    int l1 = n1 % LHW_;
    int y1 = l1 / HW_, x1 = l1 - y1 * HW_;
    #pragma unroll
    for (int t = 0; t < 9; ++t) {
      int dy = t / 3 - 1, dx = t % 3 - 1;
      if ((unsigned)(y0 + dy) < (unsigned)HW_ && (unsigned)(x0 + dx) < (unsigned)HW_)
        okm0 |= 1u << t;
      if ((unsigned)(y1 + dy) < (unsigned)HW_ && (unsigned)(x1 + dx) < (unsigned)HW_)
        okm1 |= 1u << t;
    }
    xp0 = xin + (size_t)n0 * CIN_ + jC * 8;
    xp1 = xin + (size_t)n1 * CIN_ + jC * 8;
  }

  auto stageA = [&](int kt, int h, int p) {   // p = A-read-half 0/1
    const int c = jC * 256 + p * 128 + t7;
    const u16* s = wb4 + ((size_t)kt * 2048 + c) * 8;
    u16* d = alds[h] + (size_t)(c & ~63) * 8;
    gload_lds16(s, d);
    gload_lds16(s + 8192, d + 8192);          // kgrp += 4
  };
  auto stageB = [&](int kt, int h, int p) {   // p = B-read-half 0/1
    const int t    = kt >> 1;
    const int dy   = t / 3, dx = t - dy * 3;
    const int doff = ((dy - 1) * HW_ + (dx - 1)) * CIN_ + ((kt & 1) << 6);
    const bool ok  = ((p ? okm1 : okm0) >> t) & 1;
    const u16* s   = ok ? (p ? xp1 : xp0) + doff : zpage;
    const u16* s2  = ok ? s + 32 : zpage;     // kgrp += 4
    const int c = jC * 256 + p * 128 + t7;
    u16* d = blds[h] + (size_t)(c & ~63) * 8;
    gload_lds16(s, d);
    gload_lds16(s2, d + 8192);
  };

  // frag LDS bases (u16)
  const int abase = (lg * 256 + wm * 64 + lr) * 8;
  const int bbase = (lg * 256 + wn * 32 + lr) * 8;

  f32x4 acc[8][4];
  #pragma unroll
  for (int i = 0; i < 8; ++i)
    #pragma unroll
    for (int j = 0; j < 4; ++j)
      acc[i][j] = f32x4{0.f, 0.f, 0.f, 0.f};

  short8v Af[8];            // current A-half frags [kk*4 + ai]
  short8v Bf0[4], Bf1[4];   // B half frags [kk*2 + nj]

#define READ_A(h, half)                                                         \
  { _Pragma("unroll") for (int kk = 0; kk < 2; ++kk)                            \
    _Pragma("unroll") for (int ai = 0; ai < 4; ++ai)                            \
      Af[kk * 4 + ai] = *reinterpret_cast<const short8v*>(                      \
          &alds[h][abase + kk * 8192 + (half) * 1024 + ai * 128]); }
#define READ_B(h, half, Bf)                                                     \
  { _Pragma("unroll") for (int kk = 0; kk < 2; ++kk)                            \
    _Pragma("unroll") for (int nj = 0; nj < 2; ++nj)                            \
      (Bf)[kk * 2 + nj] = *reinterpret_cast<const short8v*>(                    \
          &blds[h][bbase + kk * 8192 + (half) * 1024 + nj * 128]); }
#define PHASE_SYNC()                                                            \
  __builtin_amdgcn_sched_barrier(0);                                            \
  __builtin_amdgcn_s_barrier();                                                 \
  asm volatile("s_waitcnt lgkmcnt(0)" ::: "memory");                            \
  __builtin_amdgcn_sched_barrier(0);
#define MFMA16(ah, bh, Bf)                                                      \
  { __builtin_amdgcn_s_setprio(1);                                              \
    _Pragma("unroll") for (int kk = 0; kk < 2; ++kk)                            \
    _Pragma("unroll") for (int ai = 0; ai < 4; ++ai)                            \
    _Pragma("unroll") for (int nj = 0; nj < 2; ++nj)                            \
      acc[(ah) * 4 + ai][(bh) * 2 + nj] = __builtin_amdgcn_mfma_f32_16x16x32_bf16( \
          Af[kk * 4 + ai], (Bf)[kk * 2 + nj], acc[(ah) * 4 + ai][(bh) * 2 + nj], \
          0, 0, 0);                                                             \
    __builtin_amdgcn_s_setprio(0);                                              \
    __builtin_amdgcn_sched_barrier(0);                                          \
    __builtin_amdgcn_s_barrier(); }

  // prologue: stage all 4 half-tiles of K-tile 0 (8 VMEM instrs in flight)
  stageA(0, 0, 0); stageA(0, 0, 1); stageB(0, 0, 0); stageB(0, 0, 1);

  #pragma unroll 1
  for (int kt = 0; kt < 18; ++kt) {
    const int h  = kt & 1;
    const int nh = h ^ 1;
    const bool pf = (kt < 17);

    // ---- P0: stage A-half0(kt+1); counted wait for kt's 8 loads; reads; MFMA
    if (pf) {
      stageA(kt + 1, nh, 0);
      asm volatile("s_waitcnt vmcnt(2)" ::: "memory");
    } else {
      asm volatile("s_waitcnt vmcnt(0)" ::: "memory");
    }
    __builtin_amdgcn_sched_barrier(0);
    __builtin_amdgcn_s_barrier();            // buffer h fully landed (all waves)
    READ_A(h, 0); READ_B(h, 0, Bf0);
    asm volatile("s_waitcnt lgkmcnt(0)" ::: "memory");
    __builtin_amdgcn_sched_barrier(0);
    MFMA16(0, 0, Bf0);
    // ---- P1: reads pre-barrier; stage A-half1(kt+1)
    READ_B(h, 1, Bf1);
    if (pf) stageA(kt + 1, nh, 1);
    PHASE_SYNC();
    MFMA16(0, 1, Bf1);
    // ---- P2: reads pre-barrier; stage B-half0(kt+1)
    READ_A(h, 1);
    if (pf) stageB(kt + 1, nh, 0);
    PHASE_SYNC();
    MFMA16(1, 0, Bf0);
    // ---- P3: stage B-half1(kt+1); MFMA directly (operands already drained)
    if (pf) stageB(kt + 1, nh, 1);
    __builtin_amdgcn_sched_barrier(0);
    MFMA16(1, 1, Bf1);
  }

  // epilogue: D col = lr (spatial), row = lg*4+rr (cout)
  #pragma unroll
  for (int nj = 0; nj < 4; ++nj) {
    const int nb0 = nt * 256 + wn * 64 + nj * 16;   // 16-aligned, LHW_%16==0
    const int ob  = nb0 / LHW_;
    const int ol  = nb0 - ob * LHW_;
    float* obp = out + (size_t)ob * COUT_ * LHW_ + ol + lr;
    #pragma unroll
    for (int ai = 0; ai < 8; ++ai) {
      const int o = wm * 128 + ai * 16 + lg * 4;
      const float4 bs = *reinterpret_cast<const float4*>(&bias[o]);
      obp[(size_t)(o + 0) * LHW_] = acc[ai][nj][0] + bs.x;
      obp[(size_t)(o + 1) * LHW_] = acc[ai][nj][1] + bs.y;
      obp[(size_t)(o + 2) * LHW_] = acc[ai][nj][2] + bs.z;
      obp[(size_t)(o + 3) * LHW_] = acc[ai][nj][3] + bs.w;
    }
  }
#undef READ_A
#undef READ_B
#undef PHASE_SYNC
#undef MFMA16
}

// ---------------- fallback A (ws fits wb only): round-2 kernel ----
#define NF_    7
#define SCOLS_ 58
#define SPP_   232
#define CSTR_  128
__global__ __launch_bounds__(256, 2) void conv2_kernel(
    const float* __restrict__ in, const u16* __restrict__ wb,
    const float* __restrict__ bias, float* __restrict__ out)
{
  __shared__ u16 xs[SPP_ * CSTR_];
  const int tid  = threadIdx.x;
  const int lane = tid & 63;
  const int wid  = tid >> 6;
  const int lr   = lane & 15;
  const int lg   = lane >> 4;
  const int bid = blockIdx.x;
  const int ch  = bid & 1;
  const int ty  = (bid >> 1) % 28;
  const int b   = bid / 56;
  const float* inb = in + (size_t)b * CIN_ * LHW_;
  const int iy0 = ty * 2 - 1;

  #pragma unroll 1
  for (int i = 0; i < 15; ++i) {
    int idx = i * 256 + tid;
    if (idx < SPP_ * 16) {
      int cg  = idx / SPP_;
      int spp = idx - cg * SPP_;
      int rr  = spp / SCOLS_;
      int cc  = spp - rr * SCOLS_;
      int iy  = iy0 + rr;
      int ix  = cc - 1;
      bool ok = ((unsigned)iy < (unsigned)HW_) && ((unsigned)ix < (unsigned)HW_);
      const float* pp = inb + (size_t)cg * 8 * LHW_ + iy * HW_ + ix;
      u16 v[8];
      #pragma unroll
      for (int jj = 0; jj < 8; ++jj)
        v[jj] = f2bf(ok ? pp[jj * LHW_] : 0.f);
      uint4 pk;
      pk.x = pack2(v[0], v[1]); pk.y = pack2(v[2], v[3]);
      pk.z = pack2(v[4], v[5]); pk.w = pack2(v[6], v[7]);
      *reinterpret_cast<uint4*>(&xs[spp * CSTR_ + ((cg * 8) ^ ((spp & 7) << 3))]) = pk;
    }
  }
  int spp0[NF_];
  #pragma unroll
  for (int nf = 0; nf < NF_; ++nf) {
    int sp = nf * 16 + lr;
    int r  = (sp >= 56) ? 1 : 0;
    int x  = sp - r * 56;
    spp0[nf] = (r + 1) * SCOLS_ + x + 1;
  }
  f32x4 acc[2][NF_];
  #pragma unroll
  for (int m = 0; m < 2; ++m)
    #pragma unroll
    for (int nf = 0; nf < NF_; ++nf)
      acc[m][nf] = f32x4{0.f, 0.f, 0.f, 0.f};
  __syncthreads();
  const u16* wt0 = wb + (size_t)(ch * 128 + wid * 32 + lr) * CSTR_ + lg * 8;
  #pragma unroll 1
  for (int t = 0; t < 9; ++t) {
    const int dspp = (t / 3 - 1) * SCOLS_ + (t % 3 - 1);
    const u16* wt = wt0 + (size_t)t * 256 * CSTR_;
    #pragma unroll
    for (int c0i = 0; c0i < 4; ++c0i) {
      const int c0 = c0i * 32;
      short8v a0 = *reinterpret_cast<const short8v*>(wt + c0);
      short8v a1 = *reinterpret_cast<const short8v*>(wt + 16 * CSTR_ + c0);
      short8v bv[NF_];
      #pragma unroll
      for (int nf = 0; nf < NF_; ++nf) {
        int spp = spp0[nf] + dspp;
        int off = spp * CSTR_ + ((c0 + lg * 8) ^ ((spp & 7) << 3));
        bv[nf] = *reinterpret_cast<const short8v*>(&xs[off]);
      }
      #pragma unroll
      for (int nf = 0; nf < NF_; ++nf) {
        acc[0][nf] = __builtin_amdgcn_mfma_f32_16x16x32_bf16(a0, bv[nf], acc[0][nf], 0, 0, 0);
        acc[1][nf] = __builtin_amdgcn_mfma_f32_16x16x32_bf16(a1, bv[nf], acc[1][nf], 0, 0, 0);
      }
    }
  }
  float* ob = out + (size_t)b * COUT_ * LHW_ + ty * 112;
  const int obase = ch * 128 + wid * 32 + lg * 4;
  #pragma unroll
  for (int m = 0; m < 2; ++m)
    #pragma unroll
    for (int rr = 0; rr < 4; ++rr) {
      const int o = obase + m * 16 + rr;
      const float bs = bias[o];
      #pragma unroll
      for (int nf = 0; nf < NF_; ++nf)
        ob[(size_t)o * LHW_ + nf * 16 + lr] = acc[m][nf][rr] + bs;
    }
}

// ---------------- fallback B (no ws at all): fp32-weight direct ----
#define SPT0_  64
#define BK0_   32
#define NKS0_  36
#define LDSW0_ 40
__global__ __launch_bounds__(256, 2) void conv_fb_kernel(
    const float* __restrict__ in, const float* __restrict__ wf,
    const float* __restrict__ bias, float* __restrict__ out)
{
  __shared__ u16 xs[SPT0_ * LDSW0_];
  const int tid = threadIdx.x;
  const int lane = tid & 63;
  const int wid = tid >> 6;
  const int lg = lane >> 4;
  const int lr = lane & 15;
  const int bid = blockIdx.x;
  const int b = bid / 49;
  const int l0 = (bid % 49) * SPT0_;
  const int sp = tid & 63;
  const int qq = tid >> 6;
  const int l = l0 + sp;
  const int y = l / HW_;
  const int x = l - y * HW_;
  const float* inb = in + (size_t)b * CIN_ * LHW_;
  f32x4 acc[4][4];
  #pragma unroll
  for (int i = 0; i < 4; ++i)
    #pragma unroll
    for (int j = 0; j < 4; ++j) acc[i][j] = f32x4{0.f, 0.f, 0.f, 0.f};
  auto stage_load = [&](int ks) -> uint4 {
    int kbase = ks * BK0_ + qq * 8;
    int c = kbase / 9;
    int t = kbase - c * 9;
    u16 v[8];
    #pragma unroll
    for (int j = 0; j < 8; ++j) {
      int dy = (t * 11) >> 5;
      int dx = t - 3 * dy;
      int yy = y + dy - 1, xx = x + dx - 1;
      float f = 0.f;
      if ((unsigned)yy < (unsigned)HW_ && (unsigned)xx < (unsigned)HW_)
        f = inb[(c * HW_ + yy) * HW_ + xx];
      v[j] = f2bf(f);
      ++t; if (t == 9) { t = 0; ++c; }
    }
    uint4 r;
    r.x = pack2(v[0], v[1]); r.y = pack2(v[2], v[3]);
    r.z = pack2(v[4], v[5]); r.w = pack2(v[6], v[7]);
    return r;
  };
  uint4 st = stage_load(0);
  for (int ks = 0; ks < NKS0_; ++ks) {
    __syncthreads();
    *reinterpret_cast<uint4*>(&xs[sp * LDSW0_ + qq * 8]) = st;
    __syncthreads();
    if (ks + 1 < NKS0_) st = stage_load(ks + 1);
    const int k0 = ks * BK0_;
    short8v a[4];
    #pragma unroll
    for (int ai = 0; ai < 4; ++ai) {
      const int o = wid * 64 + ai * 16 + lr;
      const float* pp = wf + (size_t)o * KTOT_ + k0 + lg * 8;
      u16 t8[8];
      #pragma unroll
      for (int j = 0; j < 8; ++j) t8[j] = f2bf(pp[j]);
      union { uint4 u; short8v s; } cv;
      cv.u.x = pack2(t8[0], t8[1]); cv.u.y = pack2(t8[2], t8[3]);
      cv.u.z = pack2(t8[4], t8[5]); cv.u.w = pack2(t8[6], t8[7]);
      a[ai] = cv.s;
    }
    short8v bv[4];
    #pragma unroll
    for (int sj = 0; sj < 4; ++sj)
      bv[sj] = *reinterpret_cast<const short8v*>(&xs[(sj * 16 + lr) * LDSW0_ + lg * 8]);
    #pragma unroll
    for (int ai = 0; ai < 4; ++ai)
      #pragma unroll
      for (int sj = 0; sj < 4; ++sj)
        acc[ai][sj] = __builtin_amdgcn_mfma_f32_16x16x32_bf16(a[ai], bv[sj], acc[ai][sj], 0, 0, 0);
  }
  float* outb = out + (size_t)b * COUT_ * LHW_ + l0;
  #pragma unroll
  for (int ai = 0; ai < 4; ++ai)
    #pragma unroll
    for (int r = 0; r < 4; ++r) {
      const int o = wid * 64 + ai * 16 + lg * 4 + r;
      const float bvs = bias[o];
      #pragma unroll
      for (int sj = 0; sj < 4; ++sj)
        outb[(size_t)o * LHW_ + sj * 16 + lr] = acc[ai][sj][r] + bvs;
    }
}

extern "C" void kernel_launch(void* const* d_in, const int* in_sizes, int n_in,
                              void* d_out, int out_size, void* d_ws, size_t ws_size,
                              hipStream_t stream) {
  (void)in_sizes; (void)n_in; (void)out_size;
  const float* in   = (const float*)d_in[0];
  const float* w    = (const float*)d_in[1];
  const float* bias = (const float*)d_in[2];
  float* out = (float*)d_out;

  const size_t wbytes  = (size_t)COUT_ * KTOT_ * sizeof(u16);        // 589824
  const size_t xbytes  = (size_t)16 * LHW_ * CIN_ * sizeof(u16);     // 12845056
  const size_t need    = wbytes + xbytes + 256;

  if (ws_size >= need) {
    u16* wb4 = (u16*)d_ws;
    u16* xin = wb4 + wbytes / 2;
    u16* zp  = xin + xbytes / 2;
    wreorder4_kernel<<<dim3(288), dim3(256), 0, stream>>>(w, wb4, zp);
    nhwc_kernel<<<dim3(784), dim3(256), 0, stream>>>(in, xin);
    conv9_kernel<<<dim3(196), dim3(512), 0, stream>>>(xin, wb4, bias, zp, out);
  } else if (ws_size >= wbytes) {
    u16* wb = (u16*)d_ws;
    wreorder_kernel<<<dim3(288), dim3(256), 0, stream>>>(w, wb);
    conv2_kernel<<<dim3(896), dim3(256), 0, stream>>>(in, wb, bias, out);
  } else {
    conv_fb_kernel<<<dim3(784), dim3(256), 0, stream>>>(in, w, bias, out);
  }
}

// Round 10
// 67.734 us; speedup vs baseline: 1.1709x; 1.0497x over previous
//
#include <hip/hip_runtime.h>
#include <hip/hip_bf16.h>

// 3x3 s1 p1 conv: B=16, CIN=128, H=W=56, COUT=256, K = 9*128.
// Pipeline: (1) wreorder3: W fp32 -> bf16, K-tile/chunk-linear wb3 (+zero page)
//           (2) nhwc:      X fp32 NCHW -> bf16 NHWC xin[b][y][x][c]
//           (3) conv10:    implicit GEMM, 224 blocks x 512 thr (8 waves 4Mx2N),
//               tile 256co x 224sp, BK=64 (tap x 64ch), A+B LDS dbuf (120KB),
//               ONE raw s_barrier + ONE vmcnt(0) per K-tile (stage-after-barrier
//               makes this WAR-safe; drained loads are a full K-tile old), all
//               intra-tile scheduling left to the compiler.
#define CIN_   128
#define HW_    56
#define LHW_   3136
#define COUT_  256
#define KTOT_  1152

typedef unsigned short u16;
typedef __attribute__((ext_vector_type(8))) short short8v;   // 8 bf16
typedef __attribute__((ext_vector_type(4))) float f32x4;

__device__ __forceinline__ u16 f2bf(float f) {
  union { float f; unsigned u; } v; v.f = f;
  unsigned u = v.u;
  u += 0x7fffu + ((u >> 16) & 1u);   // RNE
  return (u16)(u >> 16);
}
__device__ __forceinline__ unsigned pack2(u16 a, u16 b) {
  return (unsigned)a | ((unsigned)b << 16);
}

// ---- (1) K-tile-major weight reorder + zero page.
// 16B chunk s = kt*2048 + kgrp*256 + o  holds w[o][ch*9+t] for
// t = kt>>1, ch = (kt&1)*64 + kgrp*8 + 0..7  (8 bf16, k ascending).
__global__ void wreorder3_kernel(const float* __restrict__ w, u16* __restrict__ wb3,
                                 u16* __restrict__ zp) {
  if (blockIdx.x == 0 && threadIdx.x < 16) {
    uint4 z; z.x = z.y = z.z = z.w = 0u;
    reinterpret_cast<uint4*>(zp)[threadIdx.x] = z;   // 256B zero page
  }
  int j = blockIdx.x * 256 + threadIdx.x;   // 73728 = 2 * 36864
  int half = j & 1;
  int s    = j >> 1;            // chunk 0..36863
  int o    = s & 255;
  int kgrp = (s >> 8) & 7;
  int kt   = s >> 11;
  int t    = kt >> 1;
  int c    = ((kt & 1) << 6) + kgrp * 8 + half * 4;
  const float* src = w + (size_t)o * KTOT_ + (size_t)c * 9 + t;
  ushort4 r;
  r.x = f2bf(src[0]);  r.y = f2bf(src[9]);
  r.z = f2bf(src[18]); r.w = f2bf(src[27]);
  *reinterpret_cast<ushort4*>(wb3 + (size_t)s * 8 + half * 4) = r;
}

// ---- legacy weight reorder for fallback A: wb[(t*256+o)*128 + c]
__global__ void wreorder_kernel(const float* __restrict__ w, u16* __restrict__ wb) {
  int j = blockIdx.x * 256 + threadIdx.x;
  int c4 = j & 31;
  int o  = (j >> 5) & 255;
  int t  = j >> 13;
  const float* src = w + (size_t)o * KTOT_ + t;
  ushort4 r;
  r.x = f2bf(src[(c4 * 4 + 0) * 9]);
  r.y = f2bf(src[(c4 * 4 + 1) * 9]);
  r.z = f2bf(src[(c4 * 4 + 2) * 9]);
  r.w = f2bf(src[(c4 * 4 + 3) * 9]);
  *reinterpret_cast<ushort4*>(wb + ((size_t)(t * 256 + o) * 128 + c4 * 4)) = r;
}

// ---- (2) NCHW fp32 -> NHWC bf16 transpose (LDS-tiled, 64 pos x 128 ch)
#define TLDSW_ 136
__global__ __launch_bounds__(256) void nhwc_kernel(
    const float* __restrict__ in, u16* __restrict__ xin) {
  __shared__ u16 ts[64 * TLDSW_];
  const int bp = blockIdx.x;          // 784 = 16 * 49
  const int b = bp / 49;
  const int pos0 = (bp % 49) * 64;
  const int tid = threadIdx.x;
  const float* ib = in + (size_t)b * CIN_ * LHW_ + pos0;
  {
    const int p  = tid & 63;
    const int c0 = (tid >> 6) * 32;
    #pragma unroll
    for (int i = 0; i < 32; ++i)
      ts[p * TLDSW_ + c0 + i] = f2bf(ib[(size_t)(c0 + i) * LHW_ + p]);
  }
  __syncthreads();
  {
    const int p  = tid >> 2;
    const int c0 = (tid & 3) * 32;
    u16* dst = xin + ((size_t)b * LHW_ + pos0 + p) * CIN_ + c0;
    const u16* srcr = &ts[p * TLDSW_ + c0];
    #pragma unroll
    for (int j = 0; j < 4; ++j)
      reinterpret_cast<uint4*>(dst)[j] =
          *reinterpret_cast<const uint4*>(srcr + j * 8);
  }
}

// ---- (3) main conv
__device__ __forceinline__ void gload_lds16(const void* g, void* l) {
  __builtin_amdgcn_global_load_lds(
      (const __attribute__((address_space(1))) void*)g,
      (__attribute__((address_space(3))) void*)l, 16, 0, 0);
}

__global__ __launch_bounds__(512, 2) void conv10_kernel(
    const u16* __restrict__ xin, const u16* __restrict__ wb3,
    const float* __restrict__ bias, const u16* __restrict__ zpage,
    float* __restrict__ out)
{
  // A: chunk (kgrp 0..7, o 0..255) at u16 off (kgrp*256+o)*8   (32 KB/buf)
  // B: chunk (kgrp 0..7, p 0..223) at u16 off (kgrp*224+p)*8   (28 KB/buf)
  __shared__ __align__(16) u16 alds[2][16384];
  __shared__ __align__(16) u16 blds[2][14336];   // total 120 KB

  const int tid  = threadIdx.x;
  const int lane = tid & 63;
  const int wid  = tid >> 6;
  const int wm   = wid & 3;     // 64-cout slice
  const int wn   = wid >> 2;    // 112-sp half
  const int lr   = lane & 15;
  const int lg   = lane >> 4;

  const int nt = blockIdx.x;    // 0..223
  const int b  = nt / 14;       // image (3136 = 14*224: tile within one image)
  const int l0 = (nt % 14) * 224;

  // ---- B staging geometry: chunks cb = tid + i*512 (i<3), tail 1536+tid (tid<256)
  const u16* bsrc[4];
  unsigned   bok[4];
  #pragma unroll
  for (int i = 0; i < 4; ++i) {
    int cb   = i * 512 + ((i == 3) ? (tid & 255) : tid);
    int kgrp = cb / 224;
    int pos  = cb - kgrp * 224;
    int l    = l0 + pos;
    int y    = l / HW_;
    int x    = l - y * HW_;
    unsigned m = 0;
    #pragma unroll
    for (int t = 0; t < 9; ++t) {
      int dy = t / 3 - 1, dx = t % 3 - 1;
      if ((unsigned)(y + dy) < (unsigned)HW_ && (unsigned)(x + dx) < (unsigned)HW_)
        m |= 1u << t;
    }
    bok[i]  = m;
    bsrc[i] = xin + ((size_t)b * LHW_ + l) * CIN_ + kgrp * 8;
  }

  auto stage = [&](int kt, int h) {
    // A: linear stream, 4 chunks ca = tid + i*512
    const u16* sa = wb3 + ((size_t)kt * 2048 + tid) * 8;
    u16* da = alds[h] + (size_t)(tid & ~63) * 8;
    #pragma unroll
    for (int i = 0; i < 4; ++i)
      gload_lds16(sa + i * 4096, da + i * 4096);
    // B: gathered per position at tap offset
    const int t    = kt >> 1;
    const int dy   = t / 3, dx = t - dy * 3;
    const int doff = ((dy - 1) * HW_ + (dx - 1)) * CIN_ + ((kt & 1) << 6);
    #pragma unroll
    for (int i = 0; i < 3; ++i) {
      const u16* s = ((bok[i] >> t) & 1) ? bsrc[i] + doff : zpage;
      gload_lds16(s, blds[h] + (size_t)((i * 512 + tid) & ~63) * 8);
    }
    if (tid < 256) {   // waves 0-3 (wave-uniform)
      const u16* s = ((bok[3] >> t) & 1) ? bsrc[3] + doff : zpage;
      gload_lds16(s, blds[h] + (size_t)((1536 + (tid & 255)) & ~63) * 8);
    }
  };

  // frag base offsets (u16)
  const int abase = (lg * 256 + wm * 64 + lr) * 8;    // + kk*8192 + ai*128
  const int bbase = (lg * 224 + wn * 112 + lr) * 8;   // + kk*7168 + nj*128

  f32x4 acc[4][7];
  #pragma unroll
  for (int i = 0; i < 4; ++i)
    #pragma unroll
    for (int j = 0; j < 7; ++j)
      acc[i][j] = f32x4{0.f, 0.f, 0.f, 0.f};

  stage(0, 0);   // prologue: K-tile 0 in flight

  #pragma unroll 1
  for (int kt = 0; kt < 18; ++kt) {
    const int h = kt & 1;
    // drain this K-tile's stage (issued one full compute-region ago -> ~no stall)
    asm volatile("s_waitcnt vmcnt(0)" ::: "memory");
    __builtin_amdgcn_s_barrier();            // publish h; proves h^1 reads done
    asm volatile("" ::: "memory");
    if (kt < 17) stage(kt + 1, h ^ 1);       // WAR-safe: after the barrier

    // reads + MFMA, kk-grouped; compiler schedules freely (auto lgkmcnt)
    #pragma unroll
    for (int kk = 0; kk < 2; ++kk) {
      short8v a[4], bv[7];
      #pragma unroll
      for (int ai = 0; ai < 4; ++ai)
        a[ai] = *reinterpret_cast<const short8v*>(
            &alds[h][abase + kk * 8192 + ai * 128]);
      #pragma unroll
      for (int nj = 0; nj < 7; ++nj)
        bv[nj] = *reinterpret_cast<const short8v*>(
            &blds[h][bbase + kk * 7168 + nj * 128]);
      #pragma unroll
      for (int ai = 0; ai < 4; ++ai)
        #pragma unroll
        for (int nj = 0; nj < 7; ++nj)
          acc[ai][nj] = __builtin_amdgcn_mfma_f32_16x16x32_bf16(
              a[ai], bv[nj], acc[ai][nj], 0, 0, 0);
    }
    asm volatile("" ::: "memory");           // keep reads inside their K-tile
  }

  // epilogue: D col = lr (spatial), row = lg*4+rr (cout); spatial linear.
  float* ob = out + (size_t)b * COUT_ * LHW_ + l0 + wn * 112;
  #pragma unroll
  for (int ai = 0; ai < 4; ++ai) {
    #pragma unroll
    for (int rr = 0; rr < 4; ++rr) {
      const int o = wm * 64 + ai * 16 + lg * 4 + rr;
      const float bs = bias[o];
      #pragma unroll
      for (int nj = 0; nj < 7; ++nj)
        ob[(size_t)o * LHW_ + nj * 16 + lr] = acc[ai][nj][rr] + bs;
    }
  }
}

// ---------------- fallback A (ws fits wb only): round-2 kernel ----
#define NF_    7
#define SCOLS_ 58
#define SPP_   232
#define CSTR_  128
__global__ __launch_bounds__(256, 2) void conv2_kernel(
    const float* __restrict__ in, const u16* __restrict__ wb,
    const float* __restrict__ bias, float* __restrict__ out)
{
  __shared__ u16 xs[SPP_ * CSTR_];
  const int tid  = threadIdx.x;
  const int lane = tid & 63;
  const int wid  = tid >> 6;
  const int lr   = lane & 15;
  const int lg   = lane >> 4;
  const int bid = blockIdx.x;
  const int ch  = bid & 1;
  const int ty  = (bid >> 1) % 28;
  const int b   = bid / 56;
  const float* inb = in + (size_t)b * CIN_ * LHW_;
  const int iy0 = ty * 2 - 1;

  #pragma unroll 1
  for (int i = 0; i < 15; ++i) {
    int idx = i * 256 + tid;
    if (idx < SPP_ * 16) {
      int cg  = idx / SPP_;
      int spp = idx - cg * SPP_;
      int rr  = spp / SCOLS_;
      int cc  = spp - rr * SCOLS_;
      int iy  = iy0 + rr;
      int ix  = cc - 1;
      bool ok = ((unsigned)iy < (unsigned)HW_) && ((unsigned)ix < (unsigned)HW_);
      const float* pp = inb + (size_t)cg * 8 * LHW_ + iy * HW_ + ix;
      u16 v[8];
      #pragma unroll
      for (int jj = 0; jj < 8; ++jj)
        v[jj] = f2bf(ok ? pp[jj * LHW_] : 0.f);
      uint4 pk;
      pk.x = pack2(v[0], v[1]); pk.y = pack2(v[2], v[3]);
      pk.z = pack2(v[4], v[5]); pk.w = pack2(v[6], v[7]);
      *reinterpret_cast<uint4*>(&xs[spp * CSTR_ + ((cg * 8) ^ ((spp & 7) << 3))]) = pk;
    }
  }
  int spp0[NF_];
  #pragma unroll
  for (int nf = 0; nf < NF_; ++nf) {
    int sp = nf * 16 + lr;
    int r  = (sp >= 56) ? 1 : 0;
    int x  = sp - r * 56;
    spp0[nf] = (r + 1) * SCOLS_ + x + 1;
  }
  f32x4 acc[2][NF_];
  #pragma unroll
  for (int m = 0; m < 2; ++m)
    #pragma unroll
    for (int nf = 0; nf < NF_; ++nf)
      acc[m][nf] = f32x4{0.f, 0.f, 0.f, 0.f};
  __syncthreads();
  const u16* wt0 = wb + (size_t)(ch * 128 + wid * 32 + lr) * CSTR_ + lg * 8;
  #pragma unroll 1
  for (int t = 0; t < 9; ++t) {
    const int dspp = (t / 3 - 1) * SCOLS_ + (t % 3 - 1);
    const u16* wt = wt0 + (size_t)t * 256 * CSTR_;
    #pragma unroll
    for (int c0i = 0; c0i < 4; ++c0i) {
      const int c0 = c0i * 32;
      short8v a0 = *reinterpret_cast<const short8v*>(wt + c0);
      short8v a1 = *reinterpret_cast<const short8v*>(wt + 16 * CSTR_ + c0);
      short8v bv[NF_];
      #pragma unroll
      for (int nf = 0; nf < NF_; ++nf) {
        int spp = spp0[nf] + dspp;
        int off = spp * CSTR_ + ((c0 + lg * 8) ^ ((spp & 7) << 3));
        bv[nf] = *reinterpret_cast<const short8v*>(&xs[off]);
      }
      #pragma unroll
      for (int nf = 0; nf < NF_; ++nf) {
        acc[0][nf] = __builtin_amdgcn_mfma_f32_16x16x32_bf16(a0, bv[nf], acc[0][nf], 0, 0, 0);
        acc[1][nf] = __builtin_amdgcn_mfma_f32_16x16x32_bf16(a1, bv[nf], acc[1][nf], 0, 0, 0);
      }
    }
  }
  float* ob = out + (size_t)b * COUT_ * LHW_ + ty * 112;
  const int obase = ch * 128 + wid * 32 + lg * 4;
  #pragma unroll
  for (int m = 0; m < 2; ++m)
    #pragma unroll
    for (int rr = 0; rr < 4; ++rr) {
      const int o = obase + m * 16 + rr;
      const float bs = bias[o];
      #pragma unroll
      for (int nf = 0; nf < NF_; ++nf)
        ob[(size_t)o * LHW_ + nf * 16 + lr] = acc[m][nf][rr] + bs;
    }
}

// ---------------- fallback B (no ws at all): fp32-weight direct ----
#define SPT0_  64
#define BK0_   32
#define NKS0_  36
#define LDSW0_ 40
__global__ __launch_bounds__(256, 2) void conv_fb_kernel(
    const float* __restrict__ in, const float* __restrict__ wf,
    const float* __restrict__ bias, float* __restrict__ out)
{
  __shared__ u16 xs[SPT0_ * LDSW0_];
  const int tid = threadIdx.x;
  const int lane = tid & 63;
  const int wid = tid >> 6;
  const int lg = lane >> 4;
  const int lr = lane & 15;
  const int bid = blockIdx.x;
  const int b = bid / 49;
  const int l0 = (bid % 49) * SPT0_;
  const int sp = tid & 63;
  const int qq = tid >> 6;
  const int l = l0 + sp;
  const int y = l / HW_;
  const int x = l - y * HW_;
  const float* inb = in + (size_t)b * CIN_ * LHW_;
  f32x4 acc[4][4];
  #pragma unroll
  for (int i = 0; i < 4; ++i)
    #pragma unroll
    for (int j = 0; j < 4; ++j) acc[i][j] = f32x4{0.f, 0.f, 0.f, 0.f};
  auto stage_load = [&](int ks) -> uint4 {
    int kbase = ks * BK0_ + qq * 8;
    int c = kbase / 9;
    int t = kbase - c * 9;
    u16 v[8];
    #pragma unroll
    for (int j = 0; j < 8; ++j) {
      int dy = (t * 11) >> 5;
      int dx = t - 3 * dy;
      int yy = y + dy - 1, xx = x + dx - 1;
      float f = 0.f;
      if ((unsigned)yy < (unsigned)HW_ && (unsigned)xx < (unsigned)HW_)
        f = inb[(c * HW_ + yy) * HW_ + xx];
      v[j] = f2bf(f);
      ++t; if (t == 9) { t = 0; ++c; }
    }
    uint4 r;
    r.x = pack2(v[0], v[1]); r.y = pack2(v[2], v[3]);
    r.z = pack2(v[4], v[5]); r.w = pack2(v[6], v[7]);
    return r;
  };
  uint4 st = stage_load(0);
  for (int ks = 0; ks < NKS0_; ++ks) {
    __syncthreads();
    *reinterpret_cast<uint4*>(&xs[sp * LDSW0_ + qq * 8]) = st;
    __syncthreads();
    if (ks + 1 < NKS0_) st = stage_load(ks + 1);
    const int k0 = ks * BK0_;
    short8v a[4];
    #pragma unroll
    for (int ai = 0; ai < 4; ++ai) {
      const int o = wid * 64 + ai * 16 + lr;
      const float* pp = wf + (size_t)o * KTOT_ + k0 + lg * 8;
      u16 t8[8];
      #pragma unroll
      for (int j = 0; j < 8; ++j) t8[j] = f2bf(pp[j]);
      union { uint4 u; short8v s; } cv;
      cv.u.x = pack2(t8[0], t8[1]); cv.u.y = pack2(t8[2], t8[3]);
      cv.u.z = pack2(t8[4], t8[5]); cv.u.w = pack2(t8[6], t8[7]);
      a[ai] = cv.s;
    }
    short8v bv[4];
    #pragma unroll
    for (int sj = 0; sj < 4; ++sj)
      bv[sj] = *reinterpret_cast<const short8v*>(&xs[(sj * 16 + lr) * LDSW0_ + lg * 8]);
    #pragma unroll
    for (int ai = 0; ai < 4; ++ai)
      #pragma unroll
      for (int sj = 0; sj < 4; ++sj)
        acc[ai][sj] = __builtin_amdgcn_mfma_f32_16x16x32_bf16(a[ai], bv[sj], acc[ai][sj], 0, 0, 0);
  }
  float* outb = out + (size_t)b * COUT_ * LHW_ + l0;
  #pragma unroll
  for (int ai = 0; ai < 4; ++ai)
    #pragma unroll
    for (int r = 0; r < 4; ++r) {
      const int o = wid * 64 + ai * 16 + lg * 4 + r;
      const float bvs = bias[o];
      #pragma unroll
      for (int sj = 0; sj < 4; ++sj)
        outb[(size_t)o * LHW_ + sj * 16 + lr] = acc[ai][sj][r] + bvs;
    }
}

extern "C" void kernel_launch(void* const* d_in, const int* in_sizes, int n_in,
                              void* d_out, int out_size, void* d_ws, size_t ws_size,
                              hipStream_t stream) {
  (void)in_sizes; (void)n_in; (void)out_size;
  const float* in   = (const float*)d_in[0];
  const float* w    = (const float*)d_in[1];
  const float* bias = (const float*)d_in[2];
  float* out = (float*)d_out;

  const size_t wbytes  = (size_t)COUT_ * KTOT_ * sizeof(u16);        // 589824
  const size_t xbytes  = (size_t)16 * LHW_ * CIN_ * sizeof(u16);     // 12845056
  const size_t need    = wbytes + xbytes + 256;

  if (ws_size >= need) {
    u16* wb3 = (u16*)d_ws;
    u16* xin = wb3 + wbytes / 2;
    u16* zp  = xin + xbytes / 2;
    wreorder3_kernel<<<dim3(288), dim3(256), 0, stream>>>(w, wb3, zp);
    nhwc_kernel<<<dim3(784), dim3(256), 0, stream>>>(in, xin);
    conv10_kernel<<<dim3(224), dim3(512), 0, stream>>>(xin, wb3, bias, zp, out);
  } else if (ws_size >= wbytes) {
    u16* wb = (u16*)d_ws;
    wreorder_kernel<<<dim3(288), dim3(256), 0, stream>>>(w, wb);
    conv2_kernel<<<dim3(896), dim3(256), 0, stream>>>(in, wb, bias, out);
  } else {
    conv_fb_kernel<<<dim3(784), dim3(256), 0, stream>>>(in, w, bias, out);
  }
}